// Round 2
// baseline (1142.180 us; speedup 1.0000x reference)
//
#include <hip/hip_runtime.h>

#define N_NODES 100000
#define N_EDGES 1600000
#define FEAT    256
#define NCLS    64

// ---------------- degree histogram (int atomics) --------------------------
__global__ void deg_kernel(const int* __restrict__ src, const int* __restrict__ dst,
                           int* __restrict__ cnt_out, int* __restrict__ cnt_in, int nE) {
    int i = blockIdx.x * blockDim.x + threadIdx.x;
    int stride = gridDim.x * blockDim.x;
    for (int e = i; e < nE; e += stride) {
        atomicAdd(&cnt_out[src[e]], 1);
        atomicAdd(&cnt_in[dst[e]], 1);
    }
}

// ---------------- single-block exclusive scan of cnt_in -> row_start ------
__global__ __launch_bounds__(1024) void scan_kernel(const int* __restrict__ cnt_in,
                                                    int* __restrict__ row_start) {
    __shared__ int part[1024];
    int t = threadIdx.x;
    const int CH = (N_NODES + 1023) / 1024;  // 98
    int lo = t * CH;
    int hi = lo + CH; if (hi > N_NODES) hi = N_NODES;
    int s = 0;
    for (int i = lo; i < hi; ++i) s += cnt_in[i];
    part[t] = s;
    __syncthreads();
    // Hillis-Steele inclusive scan (read-all-then-write per step)
    for (int o = 1; o < 1024; o <<= 1) {
        int u = (t >= o) ? part[t - o] : 0;
        __syncthreads();
        part[t] += u;
        __syncthreads();
    }
    int run = part[t] - s;  // exclusive prefix for this chunk
    for (int i = lo; i < hi; ++i) { row_start[i] = run; run += cnt_in[i]; }
    if (t == 0) row_start[N_NODES] = part[1023];
}

// ---------------- rsqrt norms + cursor init -------------------------------
__global__ void rs_cursor_kernel(const int* __restrict__ cnt_out, const int* __restrict__ cnt_in,
                                 const int* __restrict__ row_start,
                                 float* __restrict__ rs_out, float* __restrict__ rs_in,
                                 int* __restrict__ cursor, int n) {
    int i = blockIdx.x * blockDim.x + threadIdx.x;
    if (i < n) {
        int co = cnt_out[i]; if (co < 1) co = 1;
        int ci = cnt_in[i];  if (ci < 1) ci = 1;
        rs_out[i] = rsqrtf((float)co);
        rs_in[i]  = rsqrtf((float)ci);
        cursor[i] = row_start[i];
    }
}

// ---------------- bucket scatter: CSR column (src ids grouped by dst) -----
__global__ void bucket_kernel(const int* __restrict__ src, const int* __restrict__ dst,
                              int* __restrict__ cursor, int* __restrict__ csr_src, int nE) {
    int i = blockIdx.x * blockDim.x + threadIdx.x;
    int stride = gridDim.x * blockDim.x;
    for (int e = i; e < nE; e += stride) {
        int pos = atomicAdd(&cursor[dst[e]], 1);
        csr_src[pos] = src[e];
    }
}

// ---------------- gather: agg[d] = rs_in[d] * sum_{e->d} x[src]*rs_out[src]
// One wave per dst row; lane l owns feats 4l..4l+3 (float4). Atomic-free.
__global__ __launch_bounds__(256) void gather_kernel(
    const float* __restrict__ x, const int* __restrict__ csr_src,
    const int* __restrict__ row_start, const float* __restrict__ rs_out,
    const float* __restrict__ rs_in, float* __restrict__ agg) {
    int wave = threadIdx.x >> 6;
    int lane = threadIdx.x & 63;
    int d = blockIdx.x * 4 + wave;
    if (d >= N_NODES) return;
    int e0 = row_start[d];
    int e1 = row_start[d + 1];
    float ax = 0.f, ay = 0.f, az = 0.f, aw = 0.f;
    int e = e0;
    for (; e + 1 < e1; e += 2) {
        int sa = csr_src[e];
        int sb = csr_src[e + 1];
        float ra = rs_out[sa];
        float rb = rs_out[sb];
        float4 va = *reinterpret_cast<const float4*>(x + (size_t)sa * FEAT + lane * 4);
        float4 vb = *reinterpret_cast<const float4*>(x + (size_t)sb * FEAT + lane * 4);
        ax += va.x * ra; ay += va.y * ra; az += va.z * ra; aw += va.w * ra;
        ax += vb.x * rb; ay += vb.y * rb; az += vb.z * rb; aw += vb.w * rb;
    }
    if (e < e1) {
        int sa = csr_src[e];
        float ra = rs_out[sa];
        float4 va = *reinterpret_cast<const float4*>(x + (size_t)sa * FEAT + lane * 4);
        ax += va.x * ra; ay += va.y * ra; az += va.z * ra; aw += va.w * ra;
    }
    float ri = rs_in[d];
    float4 o = make_float4(ax * ri, ay * ri, az * ri, aw * ri);
    *reinterpret_cast<float4*>(agg + (size_t)d * FEAT + lane * 4) = o;
}

// ---------------- GEMM [N,256]x[256,256] + fused epilogue -----------------
// out_row = relu(agg_row @ W + b); pooled += column-sums. (rs_in pre-folded)
__global__ __launch_bounds__(256) void gemm_epi_kernel(
    const float* __restrict__ agg, const float* __restrict__ W,
    const float* __restrict__ bias, float* __restrict__ pooled, int nrows) {
    __shared__ float As[64][36];     // pad 36: 16B-aligned rows, 2-way banks (free)
    __shared__ float Bs[32][256];
    __shared__ float pool_lds[256];

    int tid = threadIdx.x;
    pool_lds[tid] = 0.0f;            // visible after first __syncthreads in k-loop
    int row0 = blockIdx.x * 64;
    int tr = tid >> 5;               // 0..7  -> rows tr*8..tr*8+7
    int tc = tid & 31;               // 0..31 -> cols c*32+tc

    float acc[8][8];
#pragma unroll
    for (int r = 0; r < 8; ++r)
#pragma unroll
        for (int c = 0; c < 8; ++c) acc[r][c] = 0.0f;

    for (int k0 = 0; k0 < FEAT; k0 += 32) {
#pragma unroll
        for (int i = 0; i < 2; ++i) {
            int idx = tid + i * 256;        // 0..511
            int r  = idx >> 3;
            int c4 = idx & 7;
            float4 v = make_float4(0.f, 0.f, 0.f, 0.f);
            int gr = row0 + r;
            if (gr < nrows) v = *reinterpret_cast<const float4*>(agg + (size_t)gr * FEAT + k0 + c4 * 4);
            *reinterpret_cast<float4*>(&As[r][c4 * 4]) = v;
        }
#pragma unroll
        for (int i = 0; i < 8; ++i) {
            int idx = tid + i * 256;
            int r  = idx >> 6;
            int c4 = idx & 63;
            *reinterpret_cast<float4*>(&Bs[r][c4 * 4]) =
                *reinterpret_cast<const float4*>(W + (size_t)(k0 + r) * FEAT + c4 * 4);
        }
        __syncthreads();
#pragma unroll
        for (int kk = 0; kk < 32; kk += 4) {
            float4 av[8];
#pragma unroll
            for (int r = 0; r < 8; ++r)
                av[r] = *reinterpret_cast<const float4*>(&As[tr * 8 + r][kk]);
#pragma unroll
            for (int q = 0; q < 4; ++q) {
                float bb[8];
#pragma unroll
                for (int c = 0; c < 8; ++c) bb[c] = Bs[kk + q][c * 32 + tc];
#pragma unroll
                for (int r = 0; r < 8; ++r) {
                    float a = (&av[r].x)[q];
#pragma unroll
                    for (int c = 0; c < 8; ++c) acc[r][c] += a * bb[c];
                }
            }
        }
        __syncthreads();
    }

    float csum[8];
#pragma unroll
    for (int c = 0; c < 8; ++c) csum[c] = 0.0f;
#pragma unroll
    for (int r = 0; r < 8; ++r) {
        int gr = row0 + tr * 8 + r;
        if (gr < nrows) {
#pragma unroll
            for (int c = 0; c < 8; ++c) {
                float v = acc[r][c] + bias[c * 32 + tc];
                csum[c] += fmaxf(v, 0.0f);
            }
        }
    }
#pragma unroll
    for (int c = 0; c < 8; ++c) atomicAdd(&pool_lds[c * 32 + tc], csum[c]);
    __syncthreads();
    atomicAdd(&pooled[tid], pool_lds[tid]);
}

// ---------------- pooled/N @ W2 + b2 -> softmax(64) -----------------------
__global__ void final_kernel(const float* __restrict__ pooled, const float* __restrict__ W2,
                             const float* __restrict__ b2, float* __restrict__ out) {
    int c = threadIdx.x;  // 64 threads = one wave
    const float invN = 1.0f / (float)N_NODES;
    float acc = 0.0f;
    for (int f = 0; f < FEAT; ++f) acc += pooled[f] * W2[f * NCLS + c];
    acc = acc * invN + b2[c];
    float m = acc;
#pragma unroll
    for (int o = 32; o > 0; o >>= 1) m = fmaxf(m, __shfl_xor(m, o));
    float e = expf(acc - m);
    float s = e;
#pragma unroll
    for (int o = 32; o > 0; o >>= 1) s += __shfl_xor(s, o);
    out[c] = e / s;
}

extern "C" void kernel_launch(void* const* d_in, const int* in_sizes, int n_in,
                              void* d_out, int out_size, void* d_ws, size_t ws_size,
                              hipStream_t stream) {
    const float* x   = (const float*)d_in[0];
    const int*   src = (const int*)d_in[1];
    const int*   dst = (const int*)d_in[2];
    const float* W   = (const float*)d_in[3];
    const float* b   = (const float*)d_in[4];
    const float* W2  = (const float*)d_in[5];
    const float* b2  = (const float*)d_in[6];
    float* out = (float*)d_out;

    // workspace layout (bytes, 16B-aligned sections)
    char* ws = (char*)d_ws;
    float* agg       = (float*)(ws);                                  // N*256 f
    char*  p         = ws + (size_t)N_NODES * FEAT * sizeof(float);   // 102,400,000
    int*   cnt_out   = (int*)(p);            p += (size_t)N_NODES * 4;        // zeroed
    int*   cnt_in    = (int*)(p);            p += (size_t)N_NODES * 4;        // zeroed
    float* pooled    = (float*)(p);          p += 256 * 4;                    // zeroed
    int*   row_start = (int*)(p);            p += ((size_t)N_NODES + 4) * 4;  // N+1 (padded)
    int*   cursor    = (int*)(p);            p += (size_t)N_NODES * 4;
    float* rs_out    = (float*)(p);          p += (size_t)N_NODES * 4;
    float* rs_in     = (float*)(p);          p += (size_t)N_NODES * 4;
    int*   csr_src   = (int*)(p);            p += (size_t)N_EDGES * 4;

    // zero cnt_out + cnt_in + pooled (contiguous)
    hipMemsetAsync(cnt_out, 0, (size_t)(2 * N_NODES) * 4 + 256 * 4, stream);

    deg_kernel<<<1024, 256, 0, stream>>>(src, dst, cnt_out, cnt_in, N_EDGES);
    scan_kernel<<<1, 1024, 0, stream>>>(cnt_in, row_start);
    rs_cursor_kernel<<<(N_NODES + 255) / 256, 256, 0, stream>>>(
        cnt_out, cnt_in, row_start, rs_out, rs_in, cursor, N_NODES);
    bucket_kernel<<<1024, 256, 0, stream>>>(src, dst, cursor, csr_src, N_EDGES);
    gather_kernel<<<(N_NODES + 3) / 4, 256, 0, stream>>>(
        x, csr_src, row_start, rs_out, rs_in, agg);
    gemm_epi_kernel<<<(N_NODES + 63) / 64, 256, 0, stream>>>(agg, W, b, pooled, N_NODES);
    final_kernel<<<1, 64, 0, stream>>>(pooled, W2, b2, out);
}

// Round 3
// 786.515 us; speedup vs baseline: 1.4522x; 1.4522x over previous
//
#include <hip/hip_runtime.h>
#include <hip/hip_bf16.h>

#define M_N  100000
#define N_E  1600000
#define FEAT 256
#define NCLS 64

typedef __attribute__((ext_vector_type(8))) short bf16x8;
typedef __attribute__((ext_vector_type(4))) float f32x4;

__device__ __forceinline__ ushort f2bf(float f) {
    __hip_bfloat16 h = __float2bfloat16(f);
    return __builtin_bit_cast(ushort, h);
}
__device__ __forceinline__ float bf2f(ushort u) {
    return __uint_as_float(((unsigned)u) << 16);
}
__device__ __forceinline__ void load_lds16(const void* g, void* l) {
    __builtin_amdgcn_global_load_lds(
        (const __attribute__((address_space(1))) void*)g,
        (__attribute__((address_space(3))) void*)l, 16, 0, 0);
}

// ---------------- degree histogram (int atomics) --------------------------
__global__ void deg_kernel(const int* __restrict__ src, const int* __restrict__ dst,
                           int* __restrict__ cnt_out, int* __restrict__ cnt_in, int nE) {
    int i = blockIdx.x * blockDim.x + threadIdx.x;
    int stride = gridDim.x * blockDim.x;
    for (int e = i; e < nE; e += stride) {
        atomicAdd(&cnt_out[src[e]], 1);
        atomicAdd(&cnt_in[dst[e]], 1);
    }
}

// ---------------- single-block exclusive scan of cnt_in -> row_start ------
__global__ __launch_bounds__(1024) void scan_kernel(const int* __restrict__ cnt_in,
                                                    int* __restrict__ row_start) {
    __shared__ int part[1024];
    int t = threadIdx.x;
    const int CH = (M_N + 1023) / 1024;  // 98
    int lo = t * CH;
    int hi = lo + CH; if (hi > M_N) hi = M_N;
    int s = 0;
    for (int i = lo; i < hi; ++i) s += cnt_in[i];
    part[t] = s;
    __syncthreads();
    for (int o = 1; o < 1024; o <<= 1) {
        int u = (t >= o) ? part[t - o] : 0;
        __syncthreads();
        part[t] += u;
        __syncthreads();
    }
    int run = part[t] - s;
    for (int i = lo; i < hi; ++i) { row_start[i] = run; run += cnt_in[i]; }
    if (t == 0) row_start[M_N] = part[1023];
}

// ---------------- rs_out + cursor init ------------------------------------
__global__ void rs_cursor_kernel(const int* __restrict__ cnt_out,
                                 const int* __restrict__ row_start,
                                 float* __restrict__ rs_out, int* __restrict__ cursor, int n) {
    int i = blockIdx.x * blockDim.x + threadIdx.x;
    if (i < n) {
        int co = cnt_out[i]; if (co < 1) co = 1;
        rs_out[i] = rsqrtf((float)co);
        cursor[i] = row_start[i];
    }
}

// ---------------- bucket scatter: src ids grouped by dst ------------------
__global__ void bucket_kernel(const int* __restrict__ src, const int* __restrict__ dst,
                              int* __restrict__ cursor, int* __restrict__ csr_src, int nE) {
    int i = blockIdx.x * blockDim.x + threadIdx.x;
    int stride = gridDim.x * blockDim.x;
    for (int e = i; e < nE; e += stride) {
        int pos = atomicAdd(&cursor[dst[e]], 1);
        csr_src[pos] = src[e];
    }
}

// ---------------- xn = bf16(x * rs_out[row]) ------------------------------
__global__ __launch_bounds__(256) void xn_kernel(const float* __restrict__ x,
                                                 const float* __restrict__ rs_out,
                                                 ushort* __restrict__ xn) {
    int i = blockIdx.x * blockDim.x + threadIdx.x;   // one float4 (4 feats)
    int stride = gridDim.x * blockDim.x;
    const int total = M_N * (FEAT / 4);
    for (; i < total; i += stride) {
        int row = i >> 6;                            // 64 float4 per row
        float r = rs_out[row];
        float4 v = *reinterpret_cast<const float4*>(x + (size_t)i * 4);
        ushort4 o;
        o.x = f2bf(v.x * r); o.y = f2bf(v.y * r);
        o.z = f2bf(v.z * r); o.w = f2bf(v.w * r);
        *reinterpret_cast<ushort4*>(xn + (size_t)i * 4) = o;
    }
}

// ---------------- Wt = bf16(W^T)  [n][k] ----------------------------------
__global__ void wt_kernel(const float* __restrict__ W, ushort* __restrict__ Wt) {
    int i = blockIdx.x * blockDim.x + threadIdx.x;
    if (i < FEAT * FEAT) {
        int k = i >> 8, n = i & 255;
        Wt[n * FEAT + k] = f2bf(W[i]);
    }
}

// ---------------- MFMA GEMM: xw = xn @ W  (bf16 in, bf16 out, f32 accum) --
// 128x128 tile, BK=32, 4 waves (2x2), each wave 64x64 via 4x4 16x16x32 frags.
__global__ __launch_bounds__(256) void gemm_xw_kernel(
    const ushort* __restrict__ xn, const ushort* __restrict__ Wt,
    ushort* __restrict__ xw) {
    __shared__ ushort As[128 * 32];   // 8KB, rows of 64B (k-minor)
    __shared__ ushort Bs[128 * 32];   // 8KB, n-major k-minor (transposed W)
    const int tid  = threadIdx.x;
    const int lane = tid & 63;
    const int w    = tid >> 6;
    const int wr   = w >> 1, wc = w & 1;
    const int m0   = blockIdx.x * 128;
    const int n0   = blockIdx.y * 128;

    f32x4 acc[4][4];
#pragma unroll
    for (int i = 0; i < 4; ++i)
#pragma unroll
        for (int j = 0; j < 4; ++j) {
            acc[i][j][0] = 0.f; acc[i][j][1] = 0.f;
            acc[i][j][2] = 0.f; acc[i][j][3] = 0.f;
        }

    const int lr = lane >> 2;          // 16 rows per 1KB segment
    const int lb = (lane & 3) * 16;    // byte within 64B row

    for (int k0 = 0; k0 < FEAT; k0 += 32) {
        __syncthreads();               // LDS consumed by previous iter
#pragma unroll
        for (int j = 0; j < 2; ++j) {
            const int seg = (w * 2 + j) * 1024;      // byte offset, 16 rows
            int row = (seg >> 6) + lr;
            int gr = m0 + row; if (gr >= M_N) gr = M_N - 1;   // clamp (write guarded)
            load_lds16((const char*)xn + (size_t)gr * 512 + k0 * 2 + lb,
                       (char*)As + seg);
            load_lds16((const char*)Wt + (size_t)(n0 + row) * 512 + k0 * 2 + lb,
                       (char*)Bs + seg);
        }
        __syncthreads();               // drains vmcnt (compiler inserts)
        bf16x8 a[4], b[4];
#pragma unroll
        for (int mi = 0; mi < 4; ++mi) {
            int row = wr * 64 + mi * 16 + (lane & 15);
            a[mi] = *(const bf16x8*)((const char*)As + row * 64 + (lane >> 4) * 16);
        }
#pragma unroll
        for (int ni = 0; ni < 4; ++ni) {
            int n = wc * 64 + ni * 16 + (lane & 15);
            b[ni] = *(const bf16x8*)((const char*)Bs + n * 64 + (lane >> 4) * 16);
        }
#pragma unroll
        for (int mi = 0; mi < 4; ++mi)
#pragma unroll
            for (int ni = 0; ni < 4; ++ni)
                acc[mi][ni] = __builtin_amdgcn_mfma_f32_16x16x32_bf16(
                    a[mi], b[ni], acc[mi][ni], 0, 0, 0);
    }

    // C/D layout: col = lane&15, row = (lane>>4)*4 + j   [m89/m91 verified]
#pragma unroll
    for (int mi = 0; mi < 4; ++mi) {
        int rbase = m0 + wr * 64 + mi * 16 + (lane >> 4) * 4;
#pragma unroll
        for (int ni = 0; ni < 4; ++ni) {
            int col = n0 + wc * 64 + ni * 16 + (lane & 15);
#pragma unroll
            for (int j = 0; j < 4; ++j) {
                int r = rbase + j;
                if (r < M_N) xw[(size_t)r * FEAT + col] = f2bf(acc[mi][ni][j]);
            }
        }
    }
}

// ---------------- gather + epilogue + pool --------------------------------
// One wave per dst row (grid-stride). lane owns feats 4l..4l+3 (8B bf16 load).
// pooled += relu(rs_in[d]*sum_{e->d} xw[src] + b); agg never materialized.
__global__ __launch_bounds__(256) void gather_pool_kernel(
    const ushort* __restrict__ xw, const int* __restrict__ csr_src,
    const int* __restrict__ row_start, const float* __restrict__ bias,
    float* __restrict__ pooled) {
    __shared__ float pool_lds[FEAT];
    int tid = threadIdx.x;
    pool_lds[tid] = 0.0f;
    __syncthreads();
    int lane = tid & 63;
    int wave = tid >> 6;
    int gw = blockIdx.x * 4 + wave;
    int nw = gridDim.x * 4;
    float b0 = bias[lane * 4 + 0], b1 = bias[lane * 4 + 1];
    float b2 = bias[lane * 4 + 2], b3 = bias[lane * 4 + 3];
    float p0 = 0.f, p1 = 0.f, p2 = 0.f, p3 = 0.f;

    for (int d = gw; d < M_N; d += nw) {
        int e0 = row_start[d], e1 = row_start[d + 1];
        float s0 = 0.f, s1 = 0.f, s2 = 0.f, s3 = 0.f;
        int e = e0;
        for (; e + 1 < e1; e += 2) {
            int sa = csr_src[e], sb = csr_src[e + 1];
            ushort4 va = *(const ushort4*)(xw + (size_t)sa * FEAT + lane * 4);
            ushort4 vb = *(const ushort4*)(xw + (size_t)sb * FEAT + lane * 4);
            s0 += bf2f(va.x) + bf2f(vb.x);
            s1 += bf2f(va.y) + bf2f(vb.y);
            s2 += bf2f(va.z) + bf2f(vb.z);
            s3 += bf2f(va.w) + bf2f(vb.w);
        }
        if (e < e1) {
            int sa = csr_src[e];
            ushort4 va = *(const ushort4*)(xw + (size_t)sa * FEAT + lane * 4);
            s0 += bf2f(va.x); s1 += bf2f(va.y); s2 += bf2f(va.z); s3 += bf2f(va.w);
        }
        float ri = rsqrtf(fmaxf((float)(e1 - e0), 1.0f));
        p0 += fmaxf(s0 * ri + b0, 0.f);
        p1 += fmaxf(s1 * ri + b1, 0.f);
        p2 += fmaxf(s2 * ri + b2, 0.f);
        p3 += fmaxf(s3 * ri + b3, 0.f);
    }
    atomicAdd(&pool_lds[lane * 4 + 0], p0);
    atomicAdd(&pool_lds[lane * 4 + 1], p1);
    atomicAdd(&pool_lds[lane * 4 + 2], p2);
    atomicAdd(&pool_lds[lane * 4 + 3], p3);
    __syncthreads();
    atomicAdd(&pooled[tid], pool_lds[tid]);
}

// ---------------- (pooled/N) @ W2 + b2 -> softmax(64) ---------------------
__global__ void final_kernel(const float* __restrict__ pooled, const float* __restrict__ W2,
                             const float* __restrict__ b2, float* __restrict__ out) {
    int c = threadIdx.x;  // 64 threads = one wave
    const float invN = 1.0f / (float)M_N;
    float acc = 0.0f;
    for (int f = 0; f < FEAT; ++f) acc += pooled[f] * W2[f * NCLS + c];
    acc = acc * invN + b2[c];
    float m = acc;
#pragma unroll
    for (int o = 32; o > 0; o >>= 1) m = fmaxf(m, __shfl_xor(m, o));
    float e = expf(acc - m);
    float s = e;
#pragma unroll
    for (int o = 32; o > 0; o >>= 1) s += __shfl_xor(s, o);
    out[c] = e / s;
}

extern "C" void kernel_launch(void* const* d_in, const int* in_sizes, int n_in,
                              void* d_out, int out_size, void* d_ws, size_t ws_size,
                              hipStream_t stream) {
    const float* x   = (const float*)d_in[0];
    const int*   src = (const int*)d_in[1];
    const int*   dst = (const int*)d_in[2];
    const float* W   = (const float*)d_in[3];
    const float* b   = (const float*)d_in[4];
    const float* W2  = (const float*)d_in[5];
    const float* b2  = (const float*)d_in[6];
    float* out = (float*)d_out;

    // workspace layout (16B-aligned sections)
    char* p = (char*)d_ws;
    ushort* xn       = (ushort*)p;  p += (size_t)M_N * FEAT * 2;      // 51.2 MB
    ushort* xw       = (ushort*)p;  p += (size_t)M_N * FEAT * 2;      // 51.2 MB
    ushort* Wt       = (ushort*)p;  p += (size_t)FEAT * FEAT * 2;     // 128 KB
    int*    cnt_out  = (int*)p;     p += (size_t)M_N * 4;             // zeroed
    int*    cnt_in   = (int*)p;     p += (size_t)M_N * 4;             // zeroed
    float*  pooled   = (float*)p;   p += 1024;                        // zeroed
    int*    row_start= (int*)p;     p += ((size_t)M_N + 8) * 4;
    int*    cursor   = (int*)p;     p += (size_t)M_N * 4;
    float*  rs_out   = (float*)p;   p += (size_t)M_N * 4;
    int*    csr_src  = (int*)p;     p += (size_t)N_E * 4;

    // zero cnt_out + cnt_in + pooled (contiguous)
    hipMemsetAsync(cnt_out, 0, (size_t)(2 * M_N) * 4 + 1024, stream);

    deg_kernel<<<1024, 256, 0, stream>>>(src, dst, cnt_out, cnt_in, N_E);
    scan_kernel<<<1, 1024, 0, stream>>>(cnt_in, row_start);
    rs_cursor_kernel<<<(M_N + 255) / 256, 256, 0, stream>>>(
        cnt_out, row_start, rs_out, cursor, M_N);
    bucket_kernel<<<1024, 256, 0, stream>>>(src, dst, cursor, csr_src, N_E);
    xn_kernel<<<2048, 256, 0, stream>>>(x, rs_out, xn);
    wt_kernel<<<(FEAT * FEAT + 255) / 256, 256, 0, stream>>>(W, Wt);
    gemm_xw_kernel<<<dim3((M_N + 127) / 128, 2), 256, 0, stream>>>(xn, Wt, xw);
    gather_pool_kernel<<<2048, 256, 0, stream>>>(xw, csr_src, row_start, b, pooled);
    final_kernel<<<1, 64, 0, stream>>>(pooled, W2, b2, out);
}

// Round 4
// 616.546 us; speedup vs baseline: 1.8525x; 1.2757x over previous
//
#include <hip/hip_runtime.h>
#include <hip/hip_bf16.h>

#define M_N  100000
#define N_E  1600000
#define FEAT 256
#define NCLS 64
#define SCAN_NB ((M_N + 255) / 256)   // 391 blocks

typedef __attribute__((ext_vector_type(8))) short bf16x8;
typedef __attribute__((ext_vector_type(4))) float f32x4;

__device__ __forceinline__ ushort f2bf(float f) {
    __hip_bfloat16 h = __float2bfloat16(f);
    return __builtin_bit_cast(ushort, h);
}
__device__ __forceinline__ float bf2f(ushort u) {
    return __uint_as_float(((unsigned)u) << 16);
}
__device__ __forceinline__ void load_lds16(const void* g, void* l) {
    __builtin_amdgcn_global_load_lds(
        (const __attribute__((address_space(1))) void*)g,
        (__attribute__((address_space(3))) void*)l, 16, 0, 0);
}

// ---------------- degree histogram (int atomics) --------------------------
__global__ void deg_kernel(const int* __restrict__ src, const int* __restrict__ dst,
                           int* __restrict__ cnt_out, int* __restrict__ cnt_in, int nE) {
    int i = blockIdx.x * blockDim.x + threadIdx.x;
    int stride = gridDim.x * blockDim.x;
    for (int e = i; e < nE; e += stride) {
        atomicAdd(&cnt_out[src[e]], 1);
        atomicAdd(&cnt_in[dst[e]], 1);
    }
}

// ---------------- scan phase A: per-block sums of cnt_in ------------------
__global__ __launch_bounds__(256) void scanA_kernel(const int* __restrict__ cnt_in,
                                                    int* __restrict__ bsum) {
    __shared__ int sh[256];
    int t = threadIdx.x;
    int i = blockIdx.x * 256 + t;
    sh[t] = (i < M_N) ? cnt_in[i] : 0;
    __syncthreads();
#pragma unroll
    for (int o = 128; o > 0; o >>= 1) {
        if (t < o) sh[t] += sh[t + o];
        __syncthreads();
    }
    if (t == 0) bsum[blockIdx.x] = sh[0];
}

// ---------------- scan phase B: exclusive scan of 391 partials ------------
__global__ __launch_bounds__(512) void scanB_kernel(int* __restrict__ bsum) {
    __shared__ int sh[512];
    int t = threadIdx.x;
    int v = (t < SCAN_NB) ? bsum[t] : 0;
    sh[t] = v;
    __syncthreads();
    for (int o = 1; o < 512; o <<= 1) {
        int u = (t >= o) ? sh[t - o] : 0;
        __syncthreads();
        sh[t] += u;
        __syncthreads();
    }
    if (t < SCAN_NB) bsum[t] = sh[t] - v;   // exclusive offsets, in place
}

// ---------------- scan phase C: row_start + cursor + rs_out ---------------
__global__ __launch_bounds__(256) void scanC_kernel(
    const int* __restrict__ cnt_in, const int* __restrict__ cnt_out,
    const int* __restrict__ bsum, int* __restrict__ row_start,
    int* __restrict__ cursor, float* __restrict__ rs_out) {
    __shared__ int sh[256];
    int t = threadIdx.x;
    int i = blockIdx.x * 256 + t;
    int v = (i < M_N) ? cnt_in[i] : 0;
    sh[t] = v;
    __syncthreads();
    for (int o = 1; o < 256; o <<= 1) {
        int u = (t >= o) ? sh[t - o] : 0;
        __syncthreads();
        sh[t] += u;
        __syncthreads();
    }
    int base = bsum[blockIdx.x];
    int excl = base + sh[t] - v;
    if (i < M_N) {
        row_start[i] = excl;
        cursor[i]    = excl;
        int co = cnt_out[i]; if (co < 1) co = 1;
        rs_out[i] = rsqrtf((float)co);
        if (i == M_N - 1) row_start[M_N] = excl + v;
    }
}

// ---------------- bucket scatter: src ids grouped by dst ------------------
__global__ void bucket_kernel(const int* __restrict__ src, const int* __restrict__ dst,
                              int* __restrict__ cursor, int* __restrict__ csr_src, int nE) {
    int i = blockIdx.x * blockDim.x + threadIdx.x;
    int stride = gridDim.x * blockDim.x;
    for (int e = i; e < nE; e += stride) {
        int pos = atomicAdd(&cursor[dst[e]], 1);
        csr_src[pos] = src[e];
    }
}

// ---------------- xn = bf16(x * rs_out[row]) ------------------------------
__global__ __launch_bounds__(256) void xn_kernel(const float* __restrict__ x,
                                                 const float* __restrict__ rs_out,
                                                 ushort* __restrict__ xn) {
    int i = blockIdx.x * blockDim.x + threadIdx.x;   // one float4 (4 feats)
    int stride = gridDim.x * blockDim.x;
    const int total = M_N * (FEAT / 4);
    for (; i < total; i += stride) {
        int row = i >> 6;                            // 64 float4 per row
        float r = rs_out[row];
        float4 v = *reinterpret_cast<const float4*>(x + (size_t)i * 4);
        ushort4 o;
        o.x = f2bf(v.x * r); o.y = f2bf(v.y * r);
        o.z = f2bf(v.z * r); o.w = f2bf(v.w * r);
        *reinterpret_cast<ushort4*>(xn + (size_t)i * 4) = o;
    }
}

// ---------------- Wt = bf16(W^T)  [n][k] ----------------------------------
__global__ void wt_kernel(const float* __restrict__ W, ushort* __restrict__ Wt) {
    int i = blockIdx.x * blockDim.x + threadIdx.x;
    if (i < FEAT * FEAT) {
        int k = i >> 8, n = i & 255;
        Wt[n * FEAT + k] = f2bf(W[i]);
    }
}

// ---------------- MFMA GEMM: xw = xn @ W  (bf16 in, bf16 out, f32 accum) --
// 128x128 tile, BK=32, 4 waves (2x2), each wave 64x64 via 4x4 16x16x32 frags.
__global__ __launch_bounds__(256) void gemm_xw_kernel(
    const ushort* __restrict__ xn, const ushort* __restrict__ Wt,
    ushort* __restrict__ xw) {
    __shared__ ushort As[128 * 32];   // 8KB, rows of 64B (k-minor)
    __shared__ ushort Bs[128 * 32];   // 8KB, n-major k-minor (transposed W)
    const int tid  = threadIdx.x;
    const int lane = tid & 63;
    const int w    = tid >> 6;
    const int wr   = w >> 1, wc = w & 1;
    const int m0   = blockIdx.x * 128;
    const int n0   = blockIdx.y * 128;

    f32x4 acc[4][4];
#pragma unroll
    for (int i = 0; i < 4; ++i)
#pragma unroll
        for (int j = 0; j < 4; ++j) {
            acc[i][j][0] = 0.f; acc[i][j][1] = 0.f;
            acc[i][j][2] = 0.f; acc[i][j][3] = 0.f;
        }

    const int lr = lane >> 2;          // 16 rows per 1KB segment
    const int lb = (lane & 3) * 16;    // byte within 64B row

    for (int k0 = 0; k0 < FEAT; k0 += 32) {
        __syncthreads();               // LDS consumed by previous iter
#pragma unroll
        for (int j = 0; j < 2; ++j) {
            const int seg = (w * 2 + j) * 1024;      // byte offset, 16 rows
            int row = (seg >> 6) + lr;
            int gr = m0 + row; if (gr >= M_N) gr = M_N - 1;   // clamp (write guarded)
            load_lds16((const char*)xn + (size_t)gr * 512 + k0 * 2 + lb,
                       (char*)As + seg);
            load_lds16((const char*)Wt + (size_t)(n0 + row) * 512 + k0 * 2 + lb,
                       (char*)Bs + seg);
        }
        __syncthreads();               // drains vmcnt (compiler inserts)
        bf16x8 a[4], b[4];
#pragma unroll
        for (int mi = 0; mi < 4; ++mi) {
            int row = wr * 64 + mi * 16 + (lane & 15);
            a[mi] = *(const bf16x8*)((const char*)As + row * 64 + (lane >> 4) * 16);
        }
#pragma unroll
        for (int ni = 0; ni < 4; ++ni) {
            int n = wc * 64 + ni * 16 + (lane & 15);
            b[ni] = *(const bf16x8*)((const char*)Bs + n * 64 + (lane >> 4) * 16);
        }
#pragma unroll
        for (int mi = 0; mi < 4; ++mi)
#pragma unroll
            for (int ni = 0; ni < 4; ++ni)
                acc[mi][ni] = __builtin_amdgcn_mfma_f32_16x16x32_bf16(
                    a[mi], b[ni], acc[mi][ni], 0, 0, 0);
    }

    // C/D layout: col = lane&15, row = (lane>>4)*4 + j   [m89/m91 verified]
#pragma unroll
    for (int mi = 0; mi < 4; ++mi) {
        int rbase = m0 + wr * 64 + mi * 16 + (lane >> 4) * 4;
#pragma unroll
        for (int ni = 0; ni < 4; ++ni) {
            int col = n0 + wc * 64 + ni * 16 + (lane & 15);
#pragma unroll
            for (int j = 0; j < 4; ++j) {
                int r = rbase + j;
                if (r < M_N) xw[(size_t)r * FEAT + col] = f2bf(acc[mi][ni][j]);
            }
        }
    }
}

// ---------------- gather + epilogue + pool --------------------------------
// One wave per dst row (grid-stride). lane owns feats 4l..4l+3 (8B bf16 load).
// pooled += relu(rs_in[d]*sum_{e->d} xw[src] + b); agg never materialized.
__global__ __launch_bounds__(256) void gather_pool_kernel(
    const ushort* __restrict__ xw, const int* __restrict__ csr_src,
    const int* __restrict__ row_start, const float* __restrict__ bias,
    float* __restrict__ pooled) {
    __shared__ float pool_lds[FEAT];
    int tid = threadIdx.x;
    pool_lds[tid] = 0.0f;
    __syncthreads();
    int lane = tid & 63;
    int wave = tid >> 6;
    int gw = blockIdx.x * 4 + wave;
    int nw = gridDim.x * 4;
    float b0 = bias[lane * 4 + 0], b1 = bias[lane * 4 + 1];
    float b2 = bias[lane * 4 + 2], b3 = bias[lane * 4 + 3];
    float p0 = 0.f, p1 = 0.f, p2 = 0.f, p3 = 0.f;

    for (int d = gw; d < M_N; d += nw) {
        int e0 = row_start[d], e1 = row_start[d + 1];
        float s0 = 0.f, s1 = 0.f, s2 = 0.f, s3 = 0.f;
        int e = e0;
        for (; e + 1 < e1; e += 2) {
            int sa = csr_src[e], sb = csr_src[e + 1];
            ushort4 va = *(const ushort4*)(xw + (size_t)sa * FEAT + lane * 4);
            ushort4 vb = *(const ushort4*)(xw + (size_t)sb * FEAT + lane * 4);
            s0 += bf2f(va.x) + bf2f(vb.x);
            s1 += bf2f(va.y) + bf2f(vb.y);
            s2 += bf2f(va.z) + bf2f(vb.z);
            s3 += bf2f(va.w) + bf2f(vb.w);
        }
        if (e < e1) {
            int sa = csr_src[e];
            ushort4 va = *(const ushort4*)(xw + (size_t)sa * FEAT + lane * 4);
            s0 += bf2f(va.x); s1 += bf2f(va.y); s2 += bf2f(va.z); s3 += bf2f(va.w);
        }
        float ri = rsqrtf(fmaxf((float)(e1 - e0), 1.0f));
        p0 += fmaxf(s0 * ri + b0, 0.f);
        p1 += fmaxf(s1 * ri + b1, 0.f);
        p2 += fmaxf(s2 * ri + b2, 0.f);
        p3 += fmaxf(s3 * ri + b3, 0.f);
    }
    atomicAdd(&pool_lds[lane * 4 + 0], p0);
    atomicAdd(&pool_lds[lane * 4 + 1], p1);
    atomicAdd(&pool_lds[lane * 4 + 2], p2);
    atomicAdd(&pool_lds[lane * 4 + 3], p3);
    __syncthreads();
    atomicAdd(&pooled[tid], pool_lds[tid]);
}

// ---------------- (pooled/N) @ W2 + b2 -> softmax(64) ---------------------
__global__ void final_kernel(const float* __restrict__ pooled, const float* __restrict__ W2,
                             const float* __restrict__ b2, float* __restrict__ out) {
    int c = threadIdx.x;  // 64 threads = one wave
    const float invN = 1.0f / (float)M_N;
    float acc = 0.0f;
    for (int f = 0; f < FEAT; ++f) acc += pooled[f] * W2[f * NCLS + c];
    acc = acc * invN + b2[c];
    float m = acc;
#pragma unroll
    for (int o = 32; o > 0; o >>= 1) m = fmaxf(m, __shfl_xor(m, o));
    float e = expf(acc - m);
    float s = e;
#pragma unroll
    for (int o = 32; o > 0; o >>= 1) s += __shfl_xor(s, o);
    out[c] = e / s;
}

extern "C" void kernel_launch(void* const* d_in, const int* in_sizes, int n_in,
                              void* d_out, int out_size, void* d_ws, size_t ws_size,
                              hipStream_t stream) {
    const float* x   = (const float*)d_in[0];
    const int*   src = (const int*)d_in[1];
    const int*   dst = (const int*)d_in[2];
    const float* W   = (const float*)d_in[3];
    const float* b   = (const float*)d_in[4];
    const float* W2  = (const float*)d_in[5];
    const float* b2  = (const float*)d_in[6];
    float* out = (float*)d_out;

    // workspace layout (16B-aligned sections)
    char* p = (char*)d_ws;
    ushort* xn       = (ushort*)p;  p += (size_t)M_N * FEAT * 2;      // 51.2 MB
    ushort* xw       = (ushort*)p;  p += (size_t)M_N * FEAT * 2;      // 51.2 MB
    ushort* Wt       = (ushort*)p;  p += (size_t)FEAT * FEAT * 2;     // 128 KB
    int*    cnt_out  = (int*)p;     p += (size_t)M_N * 4;             // zeroed
    int*    cnt_in   = (int*)p;     p += (size_t)M_N * 4;             // zeroed
    float*  pooled   = (float*)p;   p += 1024;                        // zeroed
    int*    row_start= (int*)p;     p += ((size_t)M_N + 8) * 4;
    int*    cursor   = (int*)p;     p += (size_t)M_N * 4;
    float*  rs_out   = (float*)p;   p += (size_t)M_N * 4;
    int*    bsum     = (int*)p;     p += 2048;                        // 391 partials
    int*    csr_src  = (int*)p;     p += (size_t)N_E * 4;

    // zero cnt_out + cnt_in + pooled (contiguous)
    hipMemsetAsync(cnt_out, 0, (size_t)(2 * M_N) * 4 + 1024, stream);

    deg_kernel<<<1024, 256, 0, stream>>>(src, dst, cnt_out, cnt_in, N_E);
    scanA_kernel<<<SCAN_NB, 256, 0, stream>>>(cnt_in, bsum);
    scanB_kernel<<<1, 512, 0, stream>>>(bsum);
    scanC_kernel<<<SCAN_NB, 256, 0, stream>>>(cnt_in, cnt_out, bsum,
                                              row_start, cursor, rs_out);
    bucket_kernel<<<1024, 256, 0, stream>>>(src, dst, cursor, csr_src, N_E);
    xn_kernel<<<2048, 256, 0, stream>>>(x, rs_out, xn);
    wt_kernel<<<(FEAT * FEAT + 255) / 256, 256, 0, stream>>>(W, Wt);
    gemm_xw_kernel<<<dim3((M_N + 127) / 128, 2), 256, 0, stream>>>(xn, Wt, xw);
    gather_pool_kernel<<<2048, 256, 0, stream>>>(xw, csr_src, row_start, b, pooled);
    final_kernel<<<1, 64, 0, stream>>>(pooled, W2, b2, out);
}

// Round 5
// 607.262 us; speedup vs baseline: 1.8809x; 1.0153x over previous
//
#include <hip/hip_runtime.h>
#include <hip/hip_bf16.h>

#define M_N  100000
#define N_E  1600000
#define FEAT 256
#define NCLS 64
#define SCAN_NB ((M_N + 255) / 256)   // 391 blocks

typedef __attribute__((ext_vector_type(8))) short bf16x8;
typedef __attribute__((ext_vector_type(8))) ushort u16x8;
typedef __attribute__((ext_vector_type(4))) float f32x4;

__device__ __forceinline__ ushort f2bf(float f) {
    __hip_bfloat16 h = __float2bfloat16(f);
    return __builtin_bit_cast(ushort, h);
}
__device__ __forceinline__ float bf2f(ushort u) {
    return __uint_as_float(((unsigned)u) << 16);
}
__device__ __forceinline__ void load_lds16(const void* g, void* l) {
    __builtin_amdgcn_global_load_lds(
        (const __attribute__((address_space(1))) void*)g,
        (__attribute__((address_space(3))) void*)l, 16, 0, 0);
}

// ---------------- degree histogram (int atomics) --------------------------
__global__ void deg_kernel(const int* __restrict__ src, const int* __restrict__ dst,
                           int* __restrict__ cnt_out, int* __restrict__ cnt_in, int nE) {
    int i = blockIdx.x * blockDim.x + threadIdx.x;
    int stride = gridDim.x * blockDim.x;
    for (int e = i; e < nE; e += stride) {
        atomicAdd(&cnt_out[src[e]], 1);
        atomicAdd(&cnt_in[dst[e]], 1);
    }
}

// ---------------- scan phase A: per-block sums of cnt_in ------------------
__global__ __launch_bounds__(256) void scanA_kernel(const int* __restrict__ cnt_in,
                                                    int* __restrict__ bsum) {
    __shared__ int sh[256];
    int t = threadIdx.x;
    int i = blockIdx.x * 256 + t;
    sh[t] = (i < M_N) ? cnt_in[i] : 0;
    __syncthreads();
#pragma unroll
    for (int o = 128; o > 0; o >>= 1) {
        if (t < o) sh[t] += sh[t + o];
        __syncthreads();
    }
    if (t == 0) bsum[blockIdx.x] = sh[0];
}

// ---------------- scan phase B: exclusive scan of 391 partials ------------
__global__ __launch_bounds__(512) void scanB_kernel(int* __restrict__ bsum) {
    __shared__ int sh[512];
    int t = threadIdx.x;
    int v = (t < SCAN_NB) ? bsum[t] : 0;
    sh[t] = v;
    __syncthreads();
    for (int o = 1; o < 512; o <<= 1) {
        int u = (t >= o) ? sh[t - o] : 0;
        __syncthreads();
        sh[t] += u;
        __syncthreads();
    }
    if (t < SCAN_NB) bsum[t] = sh[t] - v;   // exclusive offsets, in place
}

// ---------------- scan phase C: row_start + cursor + rs_out ---------------
__global__ __launch_bounds__(256) void scanC_kernel(
    const int* __restrict__ cnt_in, const int* __restrict__ cnt_out,
    const int* __restrict__ bsum, int* __restrict__ row_start,
    int* __restrict__ cursor, float* __restrict__ rs_out) {
    __shared__ int sh[256];
    int t = threadIdx.x;
    int i = blockIdx.x * 256 + t;
    int v = (i < M_N) ? cnt_in[i] : 0;
    sh[t] = v;
    __syncthreads();
    for (int o = 1; o < 256; o <<= 1) {
        int u = (t >= o) ? sh[t - o] : 0;
        __syncthreads();
        sh[t] += u;
        __syncthreads();
    }
    int base = bsum[blockIdx.x];
    int excl = base + sh[t] - v;
    if (i < M_N) {
        row_start[i] = excl;
        cursor[i]    = excl;
        int co = cnt_out[i]; if (co < 1) co = 1;
        rs_out[i] = rsqrtf((float)co);
        if (i == M_N - 1) row_start[M_N] = excl + v;
    }
}

// ---------------- bucket scatter: src ids grouped by dst ------------------
__global__ void bucket_kernel(const int* __restrict__ src, const int* __restrict__ dst,
                              int* __restrict__ cursor, int* __restrict__ csr_src, int nE) {
    int i = blockIdx.x * blockDim.x + threadIdx.x;
    int stride = gridDim.x * blockDim.x;
    for (int e = i; e < nE; e += stride) {
        int pos = atomicAdd(&cursor[dst[e]], 1);
        csr_src[pos] = src[e];
    }
}

// ---------------- Wt = bf16(W^T)  [n][k] ----------------------------------
__global__ void wt_kernel(const float* __restrict__ W, ushort* __restrict__ Wt) {
    int i = blockIdx.x * blockDim.x + threadIdx.x;
    if (i < FEAT * FEAT) {
        int k = i >> 8, n = i & 255;
        Wt[n * FEAT + k] = f2bf(W[i]);
    }
}

// ---------------- MFMA GEMM: xw = (x*rs_out) @ W, fused normalize+cvt -----
// 128x128 tile, BK=32, 4 waves (2x2), each wave 64x64 via 4x4 16x16x32 frags.
// A-tile: reg-staged from f32 x, scaled by rs_out[row], converted to bf16.
// B-tile: global_load_lds from pre-transposed bf16 Wt.
__global__ __launch_bounds__(256) void gemm_xw_kernel(
    const float* __restrict__ x, const float* __restrict__ rs_out,
    const ushort* __restrict__ Wt, ushort* __restrict__ xw) {
    __shared__ ushort As[128 * 32];   // 8KB, rows of 64B (k-minor)
    __shared__ ushort Bs[128 * 32];   // 8KB, n-major k-minor (transposed W)
    const int tid  = threadIdx.x;
    const int lane = tid & 63;
    const int w    = tid >> 6;
    const int wr   = w >> 1, wc = w & 1;
    const int m0   = blockIdx.x * 128;
    const int n0   = blockIdx.y * 128;

    // A staging coords: thread -> (row, 16-feat half)
    const int ar = tid >> 1;                 // 0..127
    const int ah = tid & 1;                  // 0..1
    int arow = m0 + ar; if (arow >= M_N) arow = M_N - 1;   // clamp (C-write guarded)
    const float rsA = rs_out[arow];
    const float* xrow = x + (size_t)arow * FEAT + ah * 16;

    // B staging coords (global_load_lds: wave-uniform base + lane*16)
    const int lr = lane >> 2;                // 16 rows per 1KB segment
    const int lb = (lane & 3) * 16;          // byte within 64B row

    f32x4 acc[4][4];
#pragma unroll
    for (int i = 0; i < 4; ++i)
#pragma unroll
        for (int j = 0; j < 4; ++j) {
            acc[i][j][0] = 0.f; acc[i][j][1] = 0.f;
            acc[i][j][2] = 0.f; acc[i][j][3] = 0.f;
        }

    for (int k0 = 0; k0 < FEAT; k0 += 32) {
        __syncthreads();               // LDS consumed by previous iter
        // B: 8 segments of 1KB, 2 per wave
#pragma unroll
        for (int j = 0; j < 2; ++j) {
            const int seg = (w * 2 + j) * 1024;
            int row = (seg >> 6) + lr;
            load_lds16((const char*)Wt + (size_t)(n0 + row) * 512 + k0 * 2 + lb,
                       (char*)Bs + seg);
        }
        // A: reg-stage 16 f32, scale, convert, 32B ds_write
        float4 f0 = *(const float4*)(xrow + k0 + 0);
        float4 f1 = *(const float4*)(xrow + k0 + 4);
        float4 f2 = *(const float4*)(xrow + k0 + 8);
        float4 f3 = *(const float4*)(xrow + k0 + 12);
        u16x8 lo, hi;
        lo[0] = f2bf(f0.x * rsA); lo[1] = f2bf(f0.y * rsA);
        lo[2] = f2bf(f0.z * rsA); lo[3] = f2bf(f0.w * rsA);
        lo[4] = f2bf(f1.x * rsA); lo[5] = f2bf(f1.y * rsA);
        lo[6] = f2bf(f1.z * rsA); lo[7] = f2bf(f1.w * rsA);
        hi[0] = f2bf(f2.x * rsA); hi[1] = f2bf(f2.y * rsA);
        hi[2] = f2bf(f2.z * rsA); hi[3] = f2bf(f2.w * rsA);
        hi[4] = f2bf(f3.x * rsA); hi[5] = f2bf(f3.y * rsA);
        hi[6] = f2bf(f3.z * rsA); hi[7] = f2bf(f3.w * rsA);
        *(u16x8*)((char*)As + ar * 64 + ah * 32)      = lo;
        *(u16x8*)((char*)As + ar * 64 + ah * 32 + 16) = hi;
        __syncthreads();               // drains vmcnt+lgkmcnt (compiler inserts)

        bf16x8 a[4], b[4];
#pragma unroll
        for (int mi = 0; mi < 4; ++mi) {
            int row = wr * 64 + mi * 16 + (lane & 15);
            a[mi] = *(const bf16x8*)((const char*)As + row * 64 + (lane >> 4) * 16);
        }
#pragma unroll
        for (int ni = 0; ni < 4; ++ni) {
            int n = wc * 64 + ni * 16 + (lane & 15);
            b[ni] = *(const bf16x8*)((const char*)Bs + n * 64 + (lane >> 4) * 16);
        }
#pragma unroll
        for (int mi = 0; mi < 4; ++mi)
#pragma unroll
            for (int ni = 0; ni < 4; ++ni)
                acc[mi][ni] = __builtin_amdgcn_mfma_f32_16x16x32_bf16(
                    a[mi], b[ni], acc[mi][ni], 0, 0, 0);
    }

    // C/D layout: col = lane&15, row = (lane>>4)*4 + j   [m89/m91 verified]
#pragma unroll
    for (int mi = 0; mi < 4; ++mi) {
        int rbase = m0 + wr * 64 + mi * 16 + (lane >> 4) * 4;
#pragma unroll
        for (int ni = 0; ni < 4; ++ni) {
            int col = n0 + wc * 64 + ni * 16 + (lane & 15);
#pragma unroll
            for (int j = 0; j < 4; ++j) {
                int r = rbase + j;
                if (r < M_N) xw[(size_t)r * FEAT + col] = f2bf(acc[mi][ni][j]);
            }
        }
    }
}

// ---------------- gather + epilogue + pool --------------------------------
// One wave per dst row (grid-stride). lane owns feats 4l..4l+3 (8B bf16 load).
// 4-deep edge pipeline: 4 independent 512B row-loads in flight per wave.
__global__ __launch_bounds__(256) void gather_pool_kernel(
    const ushort* __restrict__ xw, const int* __restrict__ csr_src,
    const int* __restrict__ row_start, const float* __restrict__ bias,
    float* __restrict__ pooled) {
    __shared__ float pool_lds[FEAT];
    int tid = threadIdx.x;
    pool_lds[tid] = 0.0f;
    __syncthreads();
    int lane = tid & 63;
    int wave = tid >> 6;
    int gw = blockIdx.x * 4 + wave;
    int nw = gridDim.x * 4;
    float b0 = bias[lane * 4 + 0], b1 = bias[lane * 4 + 1];
    float b2 = bias[lane * 4 + 2], b3 = bias[lane * 4 + 3];
    float p0 = 0.f, p1 = 0.f, p2 = 0.f, p3 = 0.f;

    for (int d = gw; d < M_N; d += nw) {
        int e0 = row_start[d], e1 = row_start[d + 1];
        float s0 = 0.f, s1 = 0.f, s2 = 0.f, s3 = 0.f;
        int e = e0;
        for (; e + 3 < e1; e += 4) {
            int ia = csr_src[e], ib = csr_src[e + 1];
            int ic = csr_src[e + 2], id = csr_src[e + 3];
            ushort4 va = *(const ushort4*)(xw + (size_t)ia * FEAT + lane * 4);
            ushort4 vb = *(const ushort4*)(xw + (size_t)ib * FEAT + lane * 4);
            ushort4 vc = *(const ushort4*)(xw + (size_t)ic * FEAT + lane * 4);
            ushort4 vd = *(const ushort4*)(xw + (size_t)id * FEAT + lane * 4);
            s0 += (bf2f(va.x) + bf2f(vb.x)) + (bf2f(vc.x) + bf2f(vd.x));
            s1 += (bf2f(va.y) + bf2f(vb.y)) + (bf2f(vc.y) + bf2f(vd.y));
            s2 += (bf2f(va.z) + bf2f(vb.z)) + (bf2f(vc.z) + bf2f(vd.z));
            s3 += (bf2f(va.w) + bf2f(vb.w)) + (bf2f(vc.w) + bf2f(vd.w));
        }
        for (; e < e1; ++e) {
            int ia = csr_src[e];
            ushort4 va = *(const ushort4*)(xw + (size_t)ia * FEAT + lane * 4);
            s0 += bf2f(va.x); s1 += bf2f(va.y); s2 += bf2f(va.z); s3 += bf2f(va.w);
        }
        float ri = rsqrtf(fmaxf((float)(e1 - e0), 1.0f));
        p0 += fmaxf(s0 * ri + b0, 0.f);
        p1 += fmaxf(s1 * ri + b1, 0.f);
        p2 += fmaxf(s2 * ri + b2, 0.f);
        p3 += fmaxf(s3 * ri + b3, 0.f);
    }
    atomicAdd(&pool_lds[lane * 4 + 0], p0);
    atomicAdd(&pool_lds[lane * 4 + 1], p1);
    atomicAdd(&pool_lds[lane * 4 + 2], p2);
    atomicAdd(&pool_lds[lane * 4 + 3], p3);
    __syncthreads();
    atomicAdd(&pooled[tid], pool_lds[tid]);
}

// ---------------- (pooled/N) @ W2 + b2 -> softmax(64) ---------------------
__global__ void final_kernel(const float* __restrict__ pooled, const float* __restrict__ W2,
                             const float* __restrict__ b2, float* __restrict__ out) {
    int c = threadIdx.x;  // 64 threads = one wave
    const float invN = 1.0f / (float)M_N;
    float acc = 0.0f;
    for (int f = 0; f < FEAT; ++f) acc += pooled[f] * W2[f * NCLS + c];
    acc = acc * invN + b2[c];
    float m = acc;
#pragma unroll
    for (int o = 32; o > 0; o >>= 1) m = fmaxf(m, __shfl_xor(m, o));
    float e = expf(acc - m);
    float s = e;
#pragma unroll
    for (int o = 32; o > 0; o >>= 1) s += __shfl_xor(s, o);
    out[c] = e / s;
}

extern "C" void kernel_launch(void* const* d_in, const int* in_sizes, int n_in,
                              void* d_out, int out_size, void* d_ws, size_t ws_size,
                              hipStream_t stream) {
    const float* x   = (const float*)d_in[0];
    const int*   src = (const int*)d_in[1];
    const int*   dst = (const int*)d_in[2];
    const float* W   = (const float*)d_in[3];
    const float* b   = (const float*)d_in[4];
    const float* W2  = (const float*)d_in[5];
    const float* b2  = (const float*)d_in[6];
    float* out = (float*)d_out;

    // workspace layout (16B-aligned sections)
    char* p = (char*)d_ws;
    ushort* xw       = (ushort*)p;  p += (size_t)M_N * FEAT * 2;      // 51.2 MB
    ushort* Wt       = (ushort*)p;  p += (size_t)FEAT * FEAT * 2;     // 128 KB
    int*    cnt_out  = (int*)p;     p += (size_t)M_N * 4;             // zeroed
    int*    cnt_in   = (int*)p;     p += (size_t)M_N * 4;             // zeroed
    float*  pooled   = (float*)p;   p += 1024;                        // zeroed
    int*    row_start= (int*)p;     p += ((size_t)M_N + 8) * 4;
    int*    cursor   = (int*)p;     p += (size_t)M_N * 4;
    float*  rs_out   = (float*)p;   p += (size_t)M_N * 4;
    int*    bsum     = (int*)p;     p += 2048;                        // 391 partials
    int*    csr_src  = (int*)p;     p += (size_t)N_E * 4;

    // zero cnt_out + cnt_in + pooled (contiguous)
    hipMemsetAsync(cnt_out, 0, (size_t)(2 * M_N) * 4 + 1024, stream);

    deg_kernel<<<1024, 256, 0, stream>>>(src, dst, cnt_out, cnt_in, N_E);
    scanA_kernel<<<SCAN_NB, 256, 0, stream>>>(cnt_in, bsum);
    scanB_kernel<<<1, 512, 0, stream>>>(bsum);
    scanC_kernel<<<SCAN_NB, 256, 0, stream>>>(cnt_in, cnt_out, bsum,
                                              row_start, cursor, rs_out);
    bucket_kernel<<<1024, 256, 0, stream>>>(src, dst, cursor, csr_src, N_E);
    wt_kernel<<<(FEAT * FEAT + 255) / 256, 256, 0, stream>>>(W, Wt);
    gemm_xw_kernel<<<dim3((M_N + 127) / 128, 2), 256, 0, stream>>>(x, rs_out, Wt, xw);
    gather_pool_kernel<<<2048, 256, 0, stream>>>(xw, csr_src, row_start, b, pooled);
    final_kernel<<<1, 64, 0, stream>>>(pooled, W2, b2, out);
}